// Round 5
// baseline (1157.445 us; speedup 1.0000x reference)
//
#include <hip/hip_runtime.h>
#include <cstddef>
#include <cstdint>

// RIMCell fused pipeline for MI355X (gfx950), dtype-robust (f32 or bf16 inputs).
// Scores path (top-k critical): f32 VALU split-K SGEMM. Big GEMMs (qkv, GRU
// pair, ctx): 256x256 8-wave 8-phase MFMA kernel, BK=64, double-buffered LDS,
// st-style XOR swizzle (both-sides involution via pre-swizzled global source),
// counted vmcnt (4/2, never 0 in steady state), setprio around MFMA clusters.
// v_l0 GEMM stays on the proven 128x128 2-phase kernel.

typedef unsigned short u16;
typedef __bf16 bf16x8 __attribute__((ext_vector_type(8)));
typedef float f32x4 __attribute__((ext_vector_type(4)));
typedef u16 u16x4 __attribute__((ext_vector_type(4)));

#define DEVFN static __device__ __forceinline__

DEVFN float ldin(const void* p, size_t i, int f) {
  return f ? (float)reinterpret_cast<const __bf16*>(p)[i]
           : reinterpret_cast<const float*>(p)[i];
}
DEVFN float bf2f(const u16* p, size_t i) {
  return (float)reinterpret_cast<const __bf16*>(p)[i];
}
DEVFN void f2bf(u16* p, size_t i, float v) {
  reinterpret_cast<__bf16*>(p)[i] = (__bf16)v;
}
DEVFN u16 bfbits(float v) {
  __bf16 b = (__bf16)v;
  return *reinterpret_cast<u16*>(&b);
}
DEVFN void gload16(const __bf16* g, __bf16* l) {
  __builtin_amdgcn_global_load_lds(
      (const __attribute__((address_space(1))) void*)g,
      (__attribute__((address_space(3))) void*)l, 16, 0, 0);
}

// ---------------- ws layout (bytes) ----------------
constexpr size_t OFF_FLAG = 0;
constexpr size_t OFF_MASK = 256;        // 4096*6*4 = 98304
constexpr size_t OFF_WVT  = 98560;      // 512*1024*2 = 1048576 (N padded 400->512)
constexpr size_t OFF_WQKV = 1147136;    // 6*2304*512*2 = 14155776 (q|k|v fused)
constexpr size_t OFF_WOT  = 15302912;   // 6*512*2048*2 = 12582912
constexpr size_t OFF_WXCT = 27885824;   // 6*1536*448*2 = 8257536 (K padded 400->448)
constexpr size_t OFF_WHCT = 36143360;   // 6*1536*512*2 = 9437184
constexpr size_t OFF_HY   = 45580544;   // 4096*3072*2 = 25165824
constexpr size_t OFF_XB   = 70746368;   // x cast to bf16: 4096*1024*2 = 8388608
constexpr size_t OFF_HSB  = 79134976;   // hs cast to bf16: 4096*3072*2 = 25165824
constexpr size_t ARENA    = 104300800;
constexpr size_t A_INP    = ARENA;      // inputs bf16 4096*6*448*2 = 22020096
// scores partials overlay A_INP (dead until rim_scores writes inputs):
constexpr size_t A_PK     = ARENA;              // 4*4096*64*4   = 4194304
constexpr size_t A_PQ     = ARENA + 4194304;    // 2*6*4096*64*4 = 12582912
constexpr size_t A_P1     = 126320896;
constexpr size_t A_KL     = A_P1;               // k_l0 f32 4096*64*4 = 1048576
constexpr size_t A_QL     = A_P1 + 1048576;     // q_l f32 4096*384*4 = 6291456
constexpr size_t A_VL     = A_P1 + 7340032;     // v_l0 bf16 4096*400*2 = 3276800
// GRU chunk: Ggx at A_P1, Ggh at A_P1 + R2*18432 (needs A_P1 + R2*36864)
// Attn chunk: comb at ARENA (R3*27648), ctx at ARENA + R3*27648 (R3*24576)

// ---------------- dtype detection ----------------
__global__ void rim_detect(const void* sw, int* flagp) {
  if (threadIdx.x == 0) {
    float s = 0.f;
    for (int i = 0; i < 24; i++)
      s += (float)reinterpret_cast<const __bf16*>(sw)[i];
    flagp[0] = (s > 5.5f && s < 6.5f) ? 1 : 0;
  }
}

// ---------------- f32 -> bf16 bulk cast (16B/thread) ----------------
__global__ __launch_bounds__(256)
void rim_cast(const void* __restrict__ in, u16* __restrict__ out, long n8,
              const int* __restrict__ flagp)
{
  const int f = flagp[0];
  long stride = (long)gridDim.x * 256;
  for (long u = (long)blockIdx.x * 256 + threadIdx.x; u < n8; u += stride) {
    if (f) {
      reinterpret_cast<uint4*>(out)[u] = reinterpret_cast<const uint4*>(in)[u];
    } else {
      f32x4 lo = reinterpret_cast<const f32x4*>(in)[u * 2];
      f32x4 hi = reinterpret_cast<const f32x4*>(in)[u * 2 + 1];
      bf16x8 r;
#pragma unroll
      for (int q = 0; q < 4; q++) { r[q] = (__bf16)lo[q]; r[q + 4] = (__bf16)hi[q]; }
      reinterpret_cast<bf16x8*>(out)[u] = r;
    }
  }
}

// -------- scores-path split-K SGEMM: P[kc][z][m0+32)[64] partials, f32 -------
__global__ __launch_bounds__(256)
void rim_sgemm32(const void* __restrict__ A_, long lda, long Az,
                 const void* __restrict__ W_, long Wz,
                 float* __restrict__ P, int KC,
                 const int* __restrict__ flagp)
{
  const int f = flagp[0];
  __shared__ float As[32 * 33];
  __shared__ float Ws[32 * 68];
  const int t = threadIdx.x;
  const int m0 = blockIdx.x * 32, kc = blockIdx.y, z = blockIdx.z;
  const int Z = gridDim.z;
  const int kb = kc * KC;
  const int tx = t & 15, ty = t >> 4;

  f32x4 acc[2];
#pragma unroll
  for (int i = 0; i < 2; i++)
#pragma unroll
    for (int j = 0; j < 4; j++) acc[i][j] = 0.f;

  for (int k0 = kb; k0 < kb + KC; k0 += 32) {
#pragma unroll
    for (int j = 0; j < 4; j++) {
      int idx = t + j * 256;
      int row = idx >> 5, kk = idx & 31;
      As[row * 33 + kk] =
          ldin(A_, (size_t)(m0 + row) * lda + (size_t)z * Az + k0 + kk, f);
    }
#pragma unroll
    for (int j = 0; j < 8; j++) {
      int idx = t + j * 256;
      int kk = idx >> 6, n = idx & 63;
      Ws[kk * 68 + n] = ldin(W_, (size_t)z * Wz + (size_t)(k0 + kk) * 64 + n, f);
    }
    __syncthreads();
#pragma unroll 8
    for (int kk = 0; kk < 32; kk++) {
      f32x4 wv = *reinterpret_cast<const f32x4*>(&Ws[kk * 68 + tx * 4]);
#pragma unroll
      for (int i = 0; i < 2; i++) {
        float a = As[(ty * 2 + i) * 33 + kk];
#pragma unroll
        for (int j = 0; j < 4; j++) acc[i][j] += a * wv[j];
      }
    }
    __syncthreads();
  }
  float* Pb = P + ((size_t)kc * Z + z) * (4096 * 64);
#pragma unroll
  for (int i = 0; i < 2; i++)
    *reinterpret_cast<f32x4*>(&Pb[(size_t)(m0 + ty * 2 + i) * 64 + tx * 4]) = acc[i];
}

// -------- reduce partials: C[m*ldc + z*Cz + n] = bias[n] + sum_kc P ---------
__global__ void rim_sreduce(const float* __restrict__ P, int NK, int Z,
                            float* __restrict__ C, long ldc, long Cz,
                            const void* __restrict__ bias,
                            const int* __restrict__ flagp, long total)
{
  const int f = flagp[0];
  long idx = (long)blockIdx.x * 256 + threadIdx.x;
  if (idx >= total) return;
  long z = idx / (4096 * 64);
  long r = idx - z * (4096 * 64);
  long m = r >> 6;
  int n = (int)(r & 63);
  float s = bias ? ldin(bias, n, f) : 0.f;
  for (int kc = 0; kc < NK; kc++)
    s += P[((size_t)kc * Z + z) * (4096 * 64) + r];
  C[(size_t)m * ldc + (size_t)z * Cz + n] = s;
}

// ============ 8-phase 256x256 GEMM, BK=64, 8 waves, derived waits ============
// C = A @ B^T. Requires M%256==0, N%256==0, K%64==0, K>=128.
// LDS: As[2][256x64] + Bs[2][256x64] bf16 = 128 KiB (double buffer).
// Swizzle (T2): byte ^= (row&7)<<4 at 16B-chunk granularity; applied on the
// READ side and inverted on the GLOBAL SOURCE of global_load_lds (dest linear,
// rule #21). row&7 == lane&7 for both patterns -> lane-constant XOR.
// Stage order per K-tile (2 loads each): B01, B23 | A02, A13. Waits:
// mid-tile vmcnt(4) (drains current A13), boundary vmcnt(2) (leaves next A13).
// EPI: 3 bf16 store, 4 final select. PAIR: z<6 -> set1 (Ggh), else set2 (Ggx).
template<int EPI, bool PAIR>
__global__ __launch_bounds__(512, 2)
void rim_gemm8(const u16* __restrict__ A1_, long A01, long lda1, long Az1,
               const u16* __restrict__ B1_, long Bz1,
               void* __restrict__ C1_, long C01, int K1,
               const u16* __restrict__ A2_, long A02q, long lda2, long Az2,
               const u16* __restrict__ B2_, long Bz2,
               void* __restrict__ C2_, long C02, int K2,
               long ldc, long Cz, int M, int N,
               const u16* __restrict__ hyp,
               const float* __restrict__ maskp,
               const void* __restrict__ hsp,
               const int* __restrict__ flagp)
{
  __shared__ __align__(16) __bf16 As[2][16384];
  __shared__ __align__(16) __bf16 Bs[2][16384];
  const int f = flagp[0];
  const int t = threadIdx.x;

  // XCD-aware bijective remap
  int gx = gridDim.x, gy = gridDim.y;
  int nwg = gx * gy * (int)gridDim.z;
  int wg = blockIdx.x + gx * (blockIdx.y + gy * blockIdx.z);
  {
    int q = nwg >> 3, r = nwg & 7, xc = wg & 7, ix = wg >> 3;
    wg = (xc < r ? xc * (q + 1) : r * (q + 1) + (xc - r) * q) + ix;
  }
  const int mb = wg % gx;
  const int nb = (wg / gx) % gy;
  const int zz = wg / (gx * gy);
  const int m0 = mb * 256, n0 = nb * 256;

  int sel = 0, z = zz;
  if constexpr (PAIR) { sel = (zz >= 6) ? 1 : 0; z = zz - sel * 6; }
  const long lda = sel ? lda2 : lda1;
  const int  K   = sel ? K2 : K1;
  const __bf16* Ab = sel
      ? reinterpret_cast<const __bf16*>(A2_) + (size_t)A02q + (size_t)z * Az2 +
        (size_t)m0 * lda2
      : reinterpret_cast<const __bf16*>(A1_) + (size_t)A01 + (size_t)z * Az1 +
        (size_t)m0 * lda1;
  const __bf16* Bb = sel
      ? reinterpret_cast<const __bf16*>(B2_) + (size_t)z * Bz2 + (size_t)n0 * K
      : reinterpret_cast<const __bf16*>(B1_) + (size_t)z * Bz1 + (size_t)n0 * K;
  void* Cp = sel ? C2_ : C1_;
  const long C0 = sel ? C02 : C01;

  const int lane = t & 63, w = t >> 6;
  // staging lane constants: lane covers row (q*64 + w*8 + lsR), 16B chunk lsC
  // of the pre-swizzled source (involution: lsC = (lane&7) ^ lsR).
  const int lsR = lane >> 3;
  const int lsC = (lane & 7) ^ lsR;
  // compute decomposition: wave owns rows [wm,wm+128), cols [wn,wn+64)
  const int wm = (w & 1) * 128, wn = (w >> 1) * 64;
  const int lr = lane & 15, lk = (lane >> 4) * 8;
  // swizzled read col offsets (elements) for ks=0/1: (ks*32+lk) ^ ((lane&7)<<3)
  const int sw0 = lk ^ ((lane & 7) << 3);
  const int sw1 = (32 + lk) ^ ((lane & 7) << 3);

  f32x4 acc[8][4];
#pragma unroll
  for (int i = 0; i < 8; i++)
#pragma unroll
    for (int j = 0; j < 4; j++)
#pragma unroll
      for (int r = 0; r < 4; r++) acc[i][j][r] = 0.f;

  const int NT = K >> 6;

  // part: 0 -> B quarters 0,1; 1 -> B q2,3; 2 -> A q0,q2; 3 -> A q1,q3
  auto ST = [&](int bn, int kt2, int part) {
    const size_t kc = (size_t)kt2 * 64 + (size_t)lsC * 8;
    if (part == 0) {
      gload16(Bb + (size_t)(w * 8 + lsR) * K + kc,        &Bs[bn][w * 512]);
      gload16(Bb + (size_t)(64 + w * 8 + lsR) * K + kc,   &Bs[bn][4096 + w * 512]);
    } else if (part == 1) {
      gload16(Bb + (size_t)(128 + w * 8 + lsR) * K + kc,  &Bs[bn][8192 + w * 512]);
      gload16(Bb + (size_t)(192 + w * 8 + lsR) * K + kc,  &Bs[bn][12288 + w * 512]);
    } else if (part == 2) {
      gload16(Ab + (size_t)(w * 8 + lsR) * lda + kc,      &As[bn][w * 512]);
      gload16(Ab + (size_t)(128 + w * 8 + lsR) * lda + kc, &As[bn][8192 + w * 512]);
    } else {
      gload16(Ab + (size_t)(64 + w * 8 + lsR) * lda + kc,  &As[bn][4096 + w * 512]);
      gload16(Ab + (size_t)(192 + w * 8 + lsR) * lda + kc, &As[bn][12288 + w * 512]);
    }
  };

  bf16x8 af[4][2], bg[2][2];

#define RD_A(qh)                                                               \
  _Pragma("unroll")                                                            \
  for (int i = 0; i < 4; i++) {                                                \
    af[i][0] = *reinterpret_cast<const bf16x8*>(                               \
        &Asb[(wm + (qh) * 64 + i * 16 + lr) * 64 + sw0]);                      \
    af[i][1] = *reinterpret_cast<const bf16x8*>(                               \
        &Asb[(wm + (qh) * 64 + i * 16 + lr) * 64 + sw1]);                      \
  }
#define RD_B(jh)                                                               \
  _Pragma("unroll")                                                            \
  for (int j = 0; j < 2; j++) {                                                \
    bg[j][0] = *reinterpret_cast<const bf16x8*>(                               \
        &Bsb[(wn + (jh) * 32 + j * 16 + lr) * 64 + sw0]);                      \
    bg[j][1] = *reinterpret_cast<const bf16x8*>(                               \
        &Bsb[(wn + (jh) * 32 + j * 16 + lr) * 64 + sw1]);                      \
  }
#define MM(qh, jh)                                                             \
  __builtin_amdgcn_s_setprio(1);                                               \
  _Pragma("unroll")                                                            \
  for (int i = 0; i < 4; i++)                                                  \
    _Pragma("unroll")                                                          \
    for (int j = 0; j < 2; j++)                                                \
      _Pragma("unroll")                                                        \
      for (int ks = 0; ks < 2; ks++)                                           \
        acc[(qh) * 4 + i][(jh) * 2 + j] = __builtin_amdgcn_mfma_f32_16x16x32_bf16( \
            af[i][ks], bg[j][ks], acc[(qh) * 4 + i][(jh) * 2 + j], 0, 0, 0);   \
  __builtin_amdgcn_s_setprio(0);
#define LG0                                                                    \
  asm volatile("s_waitcnt lgkmcnt(0)" ::: "memory");                           \
  __builtin_amdgcn_sched_barrier(0);
#define SB0 __builtin_amdgcn_sched_barrier(0);

  // prologue: stage tile 0 in canonical order, leave A13(0) in flight
  ST(0, 0, 0); SB0; ST(0, 0, 1); SB0; ST(0, 0, 2); SB0; ST(0, 0, 3); SB0;
  asm volatile("s_waitcnt vmcnt(2)" ::: "memory");
  __builtin_amdgcn_s_barrier();
  SB0;

  for (int kt = 0; kt < NT; ++kt) {
    const int cur = kt & 1, nxt = cur ^ 1;
    const bool pre = (kt + 1 < NT);
    const __bf16* Asb = &As[cur][0];
    const __bf16* Bsb = &Bs[cur][0];

    // phase 0: quadrant (qh=0, jh=0)
    if (pre) ST(nxt, kt + 1, 0);
    RD_A(0); RD_B(0);
    LG0;
    MM(0, 0);
    // phase 1: (0,1)
    if (pre) ST(nxt, kt + 1, 1);
    RD_B(1);
    LG0;
    MM(0, 1);
    // mid-tile: drain current A13 (leave next B01+B23 in flight)
    SB0;
    if (pre) { asm volatile("s_waitcnt vmcnt(4)" ::: "memory"); }
    else     { asm volatile("s_waitcnt vmcnt(0)" ::: "memory"); }
    __builtin_amdgcn_s_barrier();
    SB0;
    // phase 2: (1,0)
    if (pre) ST(nxt, kt + 1, 2);
    RD_A(1); RD_B(0);
    LG0;
    MM(1, 0);
    // phase 3: (1,1)
    if (pre) ST(nxt, kt + 1, 3);
    RD_B(1);
    LG0;
    MM(1, 1);
    // boundary: drain next B+A02 (leave next A13 in flight)
    if (pre) {
      SB0;
      asm volatile("s_waitcnt vmcnt(2)" ::: "memory");
      __builtin_amdgcn_s_barrier();
      SB0;
    }
  }
#undef RD_A
#undef RD_B
#undef MM
#undef LG0
#undef SB0

  const int rq = (lane >> 4) * 4;  // C/D: row=(lane>>4)*4+reg, col=lane&15
  const int cq = lane & 15;
#pragma unroll
  for (int i = 0; i < 8; i++) {
#pragma unroll
    for (int j = 0; j < 4; j++) {
      int cg = n0 + wn + j * 16 + cq;
      if (cg >= N) continue;
#pragma unroll
      for (int r = 0; r < 4; r++) {
        int rg = m0 + wm + i * 16 + rq + r;
        if (rg >= M) continue;
        float v = acc[i][j][r];
        size_t cidx = (size_t)rg * ldc + (size_t)z * Cz + cg;
        if constexpr (EPI == 3) {
          f2bf((u16*)Cp, C0 + cidx, v);
        } else {
          float mk = maskp[(size_t)rg * 6 + z];
          if (mk > 0.5f) {
            float o = v + bf2f(hyp, cidx);
            if (f) f2bf((u16*)Cp, C0 + cidx, o);
            else   reinterpret_cast<float*>(Cp)[C0 + cidx] = o;
          } else {
            if (f) reinterpret_cast<u16*>(Cp)[C0 + cidx] =
                       reinterpret_cast<const u16*>(hsp)[C0 + cidx];
            else   reinterpret_cast<float*>(Cp)[C0 + cidx] =
                       reinterpret_cast<const float*>(hsp)[C0 + cidx];
          }
        }
      }
    }
  }
}

// ---------------- GEMM: C = A @ Bt^T, 128x128 tile (small shapes) -----------
// EPI: 2 bf16+bias(dual-dtype).
template<int EPI>
__global__ __launch_bounds__(256)
void rim_gemm(const u16* __restrict__ A16, long A0, long lda, long Az,
              const u16* __restrict__ B_, long Bz,
              void* __restrict__ C_, long C0, long ldc, long Cz,
              int M, int N, int K,
              const void* __restrict__ bias,
              const int* __restrict__ flagp)
{
  __shared__ __align__(16) __bf16 As[2][128 * 32];
  __shared__ __align__(16) __bf16 Bs[2][128 * 32];
  const int f = flagp[0];
  const int t = threadIdx.x;

  int gx = gridDim.x, gy = gridDim.y;
  int nwg = gx * gy * (int)gridDim.z;
  int wg = blockIdx.x + gx * (blockIdx.y + gy * blockIdx.z);
  {
    int q = nwg >> 3, r = nwg & 7, xc = wg & 7, ix = wg >> 3;
    wg = (xc < r ? xc * (q + 1) : r * (q + 1) + (xc - r) * q) + ix;
  }
  const int mb = wg % gx;
  const int nb = (wg / gx) % gy;
  const int z  = wg / (gx * gy);
  const int m0 = mb * 128, n0 = nb * 128;

  const __bf16* Ab = reinterpret_cast<const __bf16*>(A16) + (size_t)A0 +
                     (size_t)z * Az + (size_t)m0 * lda;
  const __bf16* Bb = reinterpret_cast<const __bf16*>(B_) + (size_t)z * Bz +
                     (size_t)n0 * (size_t)K;

  const int lane = t & 63, w = t >> 6;
  const int srow = lane >> 2;
  const int skq  = (lane & 3) * 8;
  const __bf16* aS0 = Ab + (size_t)(w * 16 + srow) * lda + skq;
  const __bf16* aS1 = Ab + (size_t)((w + 4) * 16 + srow) * lda + skq;
  const __bf16* bS0 = Bb + (size_t)(w * 16 + srow) * (size_t)K + skq;
  const __bf16* bS1 = Bb + (size_t)((w + 4) * 16 + srow) * (size_t)K + skq;

  const int wm = (w & 1) * 64, wn = (w >> 1) * 64;
  const int lr = lane & 15, lk = (lane >> 4) * 8;

  f32x4 acc[4][4];
#pragma unroll
  for (int i = 0; i < 4; i++)
#pragma unroll
    for (int j = 0; j < 4; j++)
#pragma unroll
      for (int r = 0; r < 4; r++) acc[i][j][r] = 0.f;

  auto STAGE = [&](int buf, int k0) {
    gload16(aS0 + k0, &As[buf][w * 512]);
    gload16(aS1 + k0, &As[buf][(w + 4) * 512]);
    gload16(bS0 + k0, &Bs[buf][w * 512]);
    gload16(bS1 + k0, &Bs[buf][(w + 4) * 512]);
  };

  STAGE(0, 0);
  int cur = 0;
  for (int k0 = 0; k0 < K; k0 += 32) {
    __syncthreads();
    if (k0 + 32 < K) STAGE(cur ^ 1, k0 + 32);
    bf16x8 af[4], bg[4];
#pragma unroll
    for (int i = 0; i < 4; i++)
      af[i] = *reinterpret_cast<const bf16x8*>(&As[cur][(wm + i * 16 + lr) * 32 + lk]);
#pragma unroll
    for (int j = 0; j < 4; j++)
      bg[j] = *reinterpret_cast<const bf16x8*>(&Bs[cur][(wn + j * 16 + lr) * 32 + lk]);
#pragma unroll
    for (int i = 0; i < 4; i++)
#pragma unroll
      for (int j = 0; j < 4; j++)
        acc[i][j] = __builtin_amdgcn_mfma_f32_16x16x32_bf16(af[i], bg[j], acc[i][j], 0, 0, 0);
    cur ^= 1;
  }

  const int rq = (lane >> 4) * 4;
  const int cq = lane & 15;
#pragma unroll
  for (int i = 0; i < 4; i++) {
#pragma unroll
    for (int j = 0; j < 4; j++) {
      int cg = n0 + wn + j * 16 + cq;
      if (cg >= N) continue;
#pragma unroll
      for (int r = 0; r < 4; r++) {
        int rg = m0 + wm + i * 16 + rq + r;
        if (rg >= M) continue;
        float v = acc[i][j][r];
        size_t cidx = (size_t)rg * ldc + (size_t)z * Cz + cg;
        f2bf((u16*)C_, C0 + cidx, v + ldin(bias, cg, f));
      }
    }
  }
}

// ------- tiled transpose to bf16: out[z][n][k] = cvt(in[z][k][n]) -----------
__global__ __launch_bounds__(256)
void rim_transpose(const void* __restrict__ in, u16* __restrict__ out,
                   int N, int Np, int K, long in_z, long out_z,
                   const int* __restrict__ flagp)
{
  const int f = flagp[0];
  __shared__ float tile[32][33];
  int z = blockIdx.z;
  int k0 = blockIdx.x * 32, n0 = blockIdx.y * 32;
  int c = threadIdx.x & 31, r = threadIdx.x >> 5;
  for (int rr = r; rr < 32; rr += 8) {
    int k = k0 + rr, n = n0 + c;
    tile[rr][c] = (k < K && n < N)
        ? ldin(in, (size_t)z * in_z + (size_t)k * N + n, f) : 0.f;
  }
  __syncthreads();
  for (int rr = r; rr < 32; rr += 8) {
    int n = n0 + rr, k = k0 + c;
    if (n < Np && k < K)
      f2bf(out, (size_t)z * out_z + (size_t)n * K + k, tile[c][rr]);
  }
}

// ------- combined GRU weight, tiled transpose: out[u][o][i]=sum_s sw*gw[s][i][o]
__global__ __launch_bounds__(256)
void rim_gruw(const void* __restrict__ sw, const void* __restrict__ gw,
              u16* __restrict__ out, int IVp, int IVs,
              const int* __restrict__ flagp)
{
  const int f = flagp[0];
  __shared__ float lds[64 * 17];
  int u = blockIdx.z;
  int i0 = blockIdx.x * 16, o0 = blockIdx.y * 64;
  int t = threadIdx.x;
  float s0 = ldin(sw, u * 4 + 0, f), s1 = ldin(sw, u * 4 + 1, f);
  float s2 = ldin(sw, u * 4 + 2, f), s3 = ldin(sw, u * 4 + 3, f);
  int oo = t & 63, iq = t >> 6;
  size_t pl = (size_t)IVs * 1536;
#pragma unroll
  for (int r = 0; r < 4; r++) {
    int ii = iq * 4 + r;
    float acc = 0.f;
    if (i0 + ii < IVs) {
      size_t base = (size_t)(i0 + ii) * 1536 + o0 + oo;
      acc = s0 * ldin(gw, base, f) + s1 * ldin(gw, pl + base, f) +
            s2 * ldin(gw, 2 * pl + base, f) + s3 * ldin(gw, 3 * pl + base, f);
    }
    lds[oo * 17 + ii] = acc;
  }
  __syncthreads();
  int ow = t >> 2, iw = (t & 3) * 4;
  u16x4 pk;
#pragma unroll
  for (int j = 0; j < 4; j++) pk[j] = bfbits(lds[ow * 17 + iw + j]);
  *reinterpret_cast<u16x4*>(out + ((size_t)u * 1536 + o0 + ow) * IVp + i0 + iw) = pk;
}

// ---------------- scores / top-4 mask / 2-way softmax / inputs ----------------
// inputs written K-padded to 448 (zeros in [400,448)).
__global__ __launch_bounds__(256)
void rim_scores(const float* __restrict__ q_l, const float* __restrict__ k_l0,
                const void* __restrict__ bk, const u16* __restrict__ v_l0,
                const void* __restrict__ bv, float* __restrict__ maskf,
                u16* __restrict__ inputs, const int* __restrict__ flagp)
{
  const int f = flagp[0];
  int b = blockIdx.x;
  int t = threadIdx.x;
  int lane = t & 63;
  __shared__ float s0[6], s1[6], sm[6], sp[6];
  if (t < 64) {
    float kv = k_l0[(size_t)b * 64 + lane];
    for (int u = 0; u < 6; u++) {
      float p = q_l[((size_t)b * 6 + u) * 64 + lane] * kv;
      for (int off = 32; off; off >>= 1) p += __shfl_down(p, off);
      if (lane == 0) s0[u] = p * 0.125f;
    }
  } else if (t < 128) {
    float kv = ldin(bk, lane, f);
    for (int u = 0; u < 6; u++) {
      float p = q_l[((size_t)b * 6 + u) * 64 + lane] * kv;
      for (int off = 32; off; off >>= 1) p += __shfl_down(p, off);
      if (lane == 0) s1[u] = p * 0.125f;
    }
  }
  __syncthreads();
  if (t == 0) {
    for (int u = 0; u < 6; u++) {
      int cnt = 0;
      for (int u2 = 0; u2 < 6; u2++)
        if (s0[u2] > s0[u] || (s0[u2] == s0[u] && u2 < u)) cnt++;
      float mk = (cnt < 4) ? 1.0f : 0.0f;
      sm[u] = mk;
      maskf[(size_t)b * 6 + u] = mk;
      sp[u] = 1.0f / (1.0f + expf(s1[u] - s0[u]));
    }
  }
  __syncthreads();
  for (int idx = t; idx < 2688; idx += 256) {
    int u = idx / 448, j = idx - u * 448;
    float val = 0.f;
    if (j < 400)
      val = sm[u] * (sp[u] * bf2f(v_l0, (size_t)b * 400 + j) +
                     (1.0f - sp[u]) * ldin(bv, j, f));
    f2bf(inputs, ((size_t)b * 6 + u) * 448 + j, val);
  }
}

// ---------------- GRU elementwise ----------------
__global__ void rim_gru(const u16* __restrict__ Ggx, const u16* __restrict__ Ggh,
                        const void* __restrict__ hs, long R0,
                        u16* __restrict__ hy, long total,
                        const int* __restrict__ flagp)
{
  const int f = flagp[0];
  long idx = (long)blockIdx.x * 256 + threadIdx.x;
  if (idx >= total) return;
  long bu = idx >> 9;
  int h = idx & 511;
  size_t gb = (size_t)bu * 1536 + h;
  float xr = bf2f(Ggx, gb), xz = bf2f(Ggx, gb + 512), xn = bf2f(Ggx, gb + 1024);
  float hr = bf2f(Ggh, gb), hz = bf2f(Ggh, gb + 512), hn = bf2f(Ggh, gb + 1024);
  float r = 1.f / (1.f + expf(-(xr + hr)));
  float zz = 1.f / (1.f + expf(-(xz + hz)));
  float n = tanhf(xn + r * hn);
  float hv = ldin(hs, R0 + idx, f);
  f2bf(hy, idx, n + zz * (hv - n));
}

// ---------------- per-b attention: att -> softmax*mask -> ctx ----------------
// comb layout per b: [u][2304] = [q 128 | k 128 | v 2048]
__global__ __launch_bounds__(256)
void rim_attn(const u16* __restrict__ comb, const float* __restrict__ maskp,
              u16* __restrict__ ctx)
{
  int bl = blockIdx.x;
  int t = threadIdx.x;
  const __bf16* cb = reinterpret_cast<const __bf16*>(comb) + (size_t)bl * 13824;
  __shared__ float qs[1536];
  __shared__ float aps[144];
  __shared__ __align__(16) u16 vs[12288];
  for (int idx = t; idx < 1536; idx += 256) {
    int u = idx >> 8, r = idx & 255;
    qs[idx] = (float)cb[u * 2304 + r];
  }
  for (int idx = t; idx < 1536; idx += 256) {
    int u = idx >> 8, r = idx & 255;
    *reinterpret_cast<bf16x8*>(&vs[idx * 8]) =
        *reinterpret_cast<const bf16x8*>(cb + u * 2304 + 256 + r * 8);
  }
  __syncthreads();
  if (t < 144) {
    int h = t / 36, r6 = t % 36, uq = r6 / 6, uk = r6 % 6;
    float s = 0.f;
#pragma unroll
    for (int d = 0; d < 32; d++)
      s += qs[uq * 256 + h * 32 + d] * qs[uk * 256 + 128 + h * 32 + d];
    aps[t] = s * 0.17677669529663687f;
  }
  __syncthreads();
  if (t < 24) {
    int h = t / 6, uq = t % 6;
    float* row = &aps[h * 36 + uq * 6];
    float mx = row[0];
    for (int k = 1; k < 6; k++) mx = fmaxf(mx, row[k]);
    float e[6], sum = 0.f;
    for (int k = 0; k < 6; k++) { e[k] = expf(row[k] - mx); sum += e[k]; }
    float mk = maskp[(size_t)bl * 6 + uq] / sum;
    for (int k = 0; k < 6; k++) row[k] = e[k] * mk;
  }
  __syncthreads();
  for (int idx = t; idx < 12288; idx += 256) {
    int uq = idx >> 11, g = idx & 2047, h = g >> 9;
    const float* ar = &aps[h * 36 + uq * 6];
    float acc = 0.f;
#pragma unroll
    for (int k = 0; k < 6; k++) acc += ar[k] * bf2f(vs, k * 2048 + g);
    f2bf(ctx, ((size_t)bl * 6 + uq) * 2048 + g, acc);
  }
}

// ---------------- host ----------------
extern "C" void kernel_launch(void* const* d_in, const int* in_sizes, int n_in,
                              void* d_out, int out_size, void* d_ws, size_t ws_size,
                              hipStream_t stream)
{
  (void)in_sizes; (void)n_in; (void)out_size;
  const void* x   = d_in[0];
  const void* hs  = d_in[1];
  const void* Wk  = d_in[2];
  const void* bk  = d_in[3];
  const void* Wv  = d_in[4];
  const void* bv  = d_in[5];
  const void* Wq  = d_in[6];
  const void* Wq_ = d_in[7];
  const void* Wk_ = d_in[8];
  const void* Wv_ = d_in[9];
  const void* Wo_ = d_in[10];
  const void* sw  = d_in[11];
  const void* gwx = d_in[12];
  const void* gwh = d_in[13];
  char* ws = (char*)d_ws;

  int*   flagp = (int*)(ws + OFF_FLAG);
  float* maskf = (float*)(ws + OFF_MASK);
  u16* WvT   = (u16*)(ws + OFF_WVT);
  u16* WQKV  = (u16*)(ws + OFF_WQKV);
  u16* WoT   = (u16*)(ws + OFF_WOT);
  u16* WxcT  = (u16*)(ws + OFF_WXCT);
  u16* WhcT  = (u16*)(ws + OFF_WHCT);
  u16* hy    = (u16*)(ws + OFF_HY);
  u16* xb    = (u16*)(ws + OFF_XB);
  u16* hsb   = (u16*)(ws + OFF_HSB);
  u16* inputs = (u16*)(ws + A_INP);
  float* PK   = (float*)(ws + A_PK);
  float* PQ   = (float*)(ws + A_PQ);
  float* k_l0 = (float*)(ws + A_KL);
  float* q_l  = (float*)(ws + A_QL);
  u16* v_l0   = (u16*)(ws + A_VL);

  int R2 = 256, R3 = 256;
  {
    const int cand[5] = {4096, 2048, 1024, 512, 256};
    for (int i = 0; i < 5; i++)
      if (A_P1 + (size_t)cand[i] * 36864 <= ws_size) { R2 = cand[i]; break; }
    for (int i = 0; i < 5; i++)
      if (ARENA + (size_t)cand[i] * 52224 <= ws_size) { R3 = cand[i]; break; }
  }

  rim_detect<<<dim3(1), dim3(64), 0, stream>>>(sw, flagp);

  rim_cast<<<dim3(2048), dim3(256), 0, stream>>>(x, xb, 524288L, flagp);
  rim_cast<<<dim3(2048), dim3(256), 0, stream>>>(hs, hsb, 1572864L, flagp);

  auto T = [&](const void* in, u16* outp, int N, int Np, int K, long iz, long oz,
               int Z) {
    dim3 g((K + 31) / 32, (Np + 31) / 32, Z);
    rim_transpose<<<g, dim3(256), 0, stream>>>(in, outp, N, Np, K, iz, oz, flagp);
  };
  T(Wv, WvT, 400, 512, 1024, 0, 0, 1);
  T(Wq_, WQKV, 128, 128, 512, 65536, 1179648, 6);
  T(Wk_, WQKV + 65536, 128, 128, 512, 65536, 1179648, 6);
  T(Wv_, WQKV + 131072, 2048, 2048, 512, 1048576, 1179648, 6);
  T(Wo_, WoT, 512, 512, 2048, 1048576, 1048576, 6);
  rim_gruw<<<dim3(28, 24, 6), dim3(256), 0, stream>>>(sw, gwx, WxcT, 448, 400, flagp);
  rim_gruw<<<dim3(32, 24, 6), dim3(256), 0, stream>>>(sw, gwh, WhcT, 512, 512, flagp);

  // scores path: f32 split-K SGEMM (exact products -> stable top-k)
  rim_sgemm32<<<dim3(128, 4, 1), dim3(256), 0, stream>>>(
      x, 1024, 0, Wk, 0, PK, 256, flagp);
  rim_sgemm32<<<dim3(128, 2, 6), dim3(256), 0, stream>>>(
      hs, 3072, 512, Wq, 32768, PQ, 256, flagp);
  rim_sreduce<<<dim3(1024), dim3(256), 0, stream>>>(
      PK, 4, 1, k_l0, 64, 0, bk, flagp, 4096L * 64);
  rim_sreduce<<<dim3(6144), dim3(256), 0, stream>>>(
      PQ, 2, 6, q_l, 384, 64, nullptr, flagp, 6L * 4096 * 64);
  {
    dim3 g(32, 4, 1), blk(256);
    rim_gemm<2><<<g, blk, 0, stream>>>(xb, 0, 1024, 0, WvT, 0, v_l0, 0, 400, 0,
                                       4096, 400, 1024, bv, flagp);
  }
  rim_scores<<<dim3(4096), dim3(256), 0, stream>>>(q_l, k_l0, bk, v_l0, bv,
                                                   maskf, inputs, flagp);

  // GRU projections: fused z=12 8-phase dispatch (Ggh set1 | Ggx set2)
  u16* Ggx = (u16*)(ws + A_P1);
  u16* Ggh = (u16*)(ws + A_P1 + (size_t)R2 * 18432);
  for (int r0 = 0; r0 < 4096; r0 += R2) {
    dim3 g(R2 / 256, 6, 12), blk(512);
    rim_gemm8<3, true><<<g, blk, 0, stream>>>(
        hsb, (long)r0 * 3072, 3072, 512, WhcT, 786432, Ggh, 0, 512,
        inputs, (long)r0 * 2688, 2688, 448, WxcT, 688128, Ggx, 0, 448,
        9216, 1536, R2, 1536, nullptr, nullptr, nullptr, flagp);
    long total = (long)R2 * 3072;
    rim_gru<<<dim3((unsigned)(total / 256)), dim3(256), 0, stream>>>(
        Ggx, Ggh, hs, (long)r0 * 3072, hy + (size_t)r0 * 3072, total, flagp);
  }

  // attention + output in chunks of R3 rows (q|k|v fused N=2304, 8-phase)
  u16* comb  = (u16*)(ws + ARENA);
  u16* ctx_c = (u16*)(ws + ARENA + (size_t)R3 * 27648);
  for (int r0 = 0; r0 < 4096; r0 += R3) {
    {
      dim3 g(R3 / 256, 9, 6), blk(512);
      rim_gemm8<3, false><<<g, blk, 0, stream>>>(
          hy, (long)r0 * 3072, 3072, 512, WQKV, 1179648, comb, 0, 512,
          hy, (long)r0 * 3072, 3072, 512, WQKV, 1179648, comb, 0, 512,
          13824, 2304, R3, 2304, nullptr, nullptr, nullptr, flagp);
    }
    rim_attn<<<dim3(R3), dim3(256), 0, stream>>>(comb, maskf + (size_t)r0 * 6, ctx_c);
    {
      dim3 g(R3 / 256, 2, 6), blk(512);
      rim_gemm8<4, false><<<g, blk, 0, stream>>>(
          ctx_c, 0, 12288, 2048, WoT, 1048576, d_out, (long)r0 * 3072, 2048,
          ctx_c, 0, 12288, 2048, WoT, 1048576, d_out, (long)r0 * 3072, 2048,
          3072, 512, R3, 512,
          hy + (size_t)r0 * 3072, maskf + (size_t)r0 * 6, hs, flagp);
    }
  }
}

// Round 6
// 922.600 us; speedup vs baseline: 1.2545x; 1.2545x over previous
//
#include <hip/hip_runtime.h>
#include <cstddef>
#include <cstdint>

// RIMCell fused pipeline for MI355X (gfx950), dtype-robust (f32 or bf16 inputs).
// Scores path (top-k critical): f32 VALU split-K SGEMM (exact products,
// deterministic two-pass reduce). All other GEMMs: bf16 MFMA with m97-style
// global_load_lds(16B) staging, single-barrier LDS double-buffer, XCD swizzle.
// 128x128 tile (measured faster than 256x256 8-phase on these shapes: 3 blk/CU
// inter-block overlap beats deeper pipelines at 1 blk/CU -- R3/R5 regressions).
// qk+v fused (N=2304); Ggh+Ggx fused (z=12). attn/gru vectorized 8-wide.

typedef unsigned short u16;
typedef __bf16 bf16x8 __attribute__((ext_vector_type(8)));
typedef float f32x4 __attribute__((ext_vector_type(4)));
typedef u16 u16x4 __attribute__((ext_vector_type(4)));

#define DEVFN static __device__ __forceinline__

DEVFN float ldin(const void* p, size_t i, int f) {
  return f ? (float)reinterpret_cast<const __bf16*>(p)[i]
           : reinterpret_cast<const float*>(p)[i];
}
DEVFN float bf2f(const u16* p, size_t i) {
  return (float)reinterpret_cast<const __bf16*>(p)[i];
}
DEVFN void f2bf(u16* p, size_t i, float v) {
  reinterpret_cast<__bf16*>(p)[i] = (__bf16)v;
}
DEVFN u16 bfbits(float v) {
  __bf16 b = (__bf16)v;
  return *reinterpret_cast<u16*>(&b);
}
DEVFN void gload16(const __bf16* g, __bf16* l) {
  __builtin_amdgcn_global_load_lds(
      (const __attribute__((address_space(1))) void*)g,
      (__attribute__((address_space(3))) void*)l, 16, 0, 0);
}

// ---------------- ws layout (bytes) ----------------
constexpr size_t OFF_FLAG = 0;
constexpr size_t OFF_MASK = 256;        // 4096*6*4 = 98304
constexpr size_t OFF_WVT  = 98560;      // 512*1024*2 = 1048576 (N padded 400->512)
constexpr size_t OFF_WQKV = 1147136;    // 6*2304*512*2 = 14155776 (q|k|v fused)
constexpr size_t OFF_WOT  = 15302912;   // 6*512*2048*2 = 12582912
constexpr size_t OFF_WXCT = 27885824;   // 6*1536*416*2 = 7667712 (K padded 400->416)
constexpr size_t OFF_WHCT = 35553536;   // 6*1536*512*2 = 9437184
constexpr size_t OFF_HY   = 44990720;   // 4096*3072*2 = 25165824
constexpr size_t OFF_XB   = 70156544;   // x cast to bf16: 4096*1024*2 = 8388608
constexpr size_t OFF_HSB  = 78545152;   // hs cast to bf16: 4096*3072*2 = 25165824
constexpr size_t ARENA    = 103710976;
constexpr size_t A_INP    = ARENA;      // inputs bf16 4096*6*416*2 = 20447232
// scores partials overlay A_INP (dead until rim_scores writes inputs):
constexpr size_t A_PK     = ARENA;              // 4*4096*64*4   = 4194304
constexpr size_t A_PQ     = ARENA + 4194304;    // 2*6*4096*64*4 = 12582912
constexpr size_t A_P1     = 124158208;
constexpr size_t A_KL     = A_P1;               // k_l0 f32 4096*64*4 = 1048576
constexpr size_t A_QL     = A_P1 + 1048576;     // q_l f32 4096*384*4 = 6291456
constexpr size_t A_VL     = A_P1 + 7340032;     // v_l0 bf16 4096*400*2 = 3276800
// GRU chunk: Ggx at A_P1, Ggh at A_P1 + R2*18432 (needs A_P1 + R2*36864)
// Attn chunk: comb at ARENA (R3*27648), ctx at ARENA + R3*27648 (R3*24576)

// ---------------- dtype detection ----------------
__global__ void rim_detect(const void* sw, int* flagp) {
  if (threadIdx.x == 0) {
    float s = 0.f;
    for (int i = 0; i < 24; i++)
      s += (float)reinterpret_cast<const __bf16*>(sw)[i];
    flagp[0] = (s > 5.5f && s < 6.5f) ? 1 : 0;
  }
}

// ---------------- f32 -> bf16 bulk cast (16B/thread) ----------------
__global__ __launch_bounds__(256)
void rim_cast(const void* __restrict__ in, u16* __restrict__ out, long n8,
              const int* __restrict__ flagp)
{
  const int f = flagp[0];
  long stride = (long)gridDim.x * 256;
  for (long u = (long)blockIdx.x * 256 + threadIdx.x; u < n8; u += stride) {
    if (f) {
      reinterpret_cast<uint4*>(out)[u] = reinterpret_cast<const uint4*>(in)[u];
    } else {
      f32x4 lo = reinterpret_cast<const f32x4*>(in)[u * 2];
      f32x4 hi = reinterpret_cast<const f32x4*>(in)[u * 2 + 1];
      bf16x8 r;
#pragma unroll
      for (int q = 0; q < 4; q++) { r[q] = (__bf16)lo[q]; r[q + 4] = (__bf16)hi[q]; }
      reinterpret_cast<bf16x8*>(out)[u] = r;
    }
  }
}

// -------- scores-path split-K SGEMM: P[kc][z][m0+32)[64] partials, f32 -------
__global__ __launch_bounds__(256)
void rim_sgemm32(const void* __restrict__ A_, long lda, long Az,
                 const void* __restrict__ W_, long Wz,
                 float* __restrict__ P, int KC,
                 const int* __restrict__ flagp)
{
  const int f = flagp[0];
  __shared__ float As[32 * 33];
  __shared__ float Ws[32 * 68];
  const int t = threadIdx.x;
  const int m0 = blockIdx.x * 32, kc = blockIdx.y, z = blockIdx.z;
  const int Z = gridDim.z;
  const int kb = kc * KC;
  const int tx = t & 15, ty = t >> 4;

  f32x4 acc[2];
#pragma unroll
  for (int i = 0; i < 2; i++)
#pragma unroll
    for (int j = 0; j < 4; j++) acc[i][j] = 0.f;

  for (int k0 = kb; k0 < kb + KC; k0 += 32) {
#pragma unroll
    for (int j = 0; j < 4; j++) {
      int idx = t + j * 256;
      int row = idx >> 5, kk = idx & 31;
      As[row * 33 + kk] =
          ldin(A_, (size_t)(m0 + row) * lda + (size_t)z * Az + k0 + kk, f);
    }
#pragma unroll
    for (int j = 0; j < 8; j++) {
      int idx = t + j * 256;
      int kk = idx >> 6, n = idx & 63;
      Ws[kk * 68 + n] = ldin(W_, (size_t)z * Wz + (size_t)(k0 + kk) * 64 + n, f);
    }
    __syncthreads();
#pragma unroll 8
    for (int kk = 0; kk < 32; kk++) {
      f32x4 wv = *reinterpret_cast<const f32x4*>(&Ws[kk * 68 + tx * 4]);
#pragma unroll
      for (int i = 0; i < 2; i++) {
        float a = As[(ty * 2 + i) * 33 + kk];
#pragma unroll
        for (int j = 0; j < 4; j++) acc[i][j] += a * wv[j];
      }
    }
    __syncthreads();
  }
  float* Pb = P + ((size_t)kc * Z + z) * (4096 * 64);
#pragma unroll
  for (int i = 0; i < 2; i++)
    *reinterpret_cast<f32x4*>(&Pb[(size_t)(m0 + ty * 2 + i) * 64 + tx * 4]) = acc[i];
}

// -------- reduce partials: C[m*ldc + z*Cz + n] = bias[n] + sum_kc P ---------
__global__ void rim_sreduce(const float* __restrict__ P, int NK, int Z,
                            float* __restrict__ C, long ldc, long Cz,
                            const void* __restrict__ bias,
                            const int* __restrict__ flagp, long total)
{
  const int f = flagp[0];
  long idx = (long)blockIdx.x * 256 + threadIdx.x;
  if (idx >= total) return;
  long z = idx / (4096 * 64);
  long r = idx - z * (4096 * 64);
  long m = r >> 6;
  int n = (int)(r & 63);
  float s = bias ? ldin(bias, n, f) : 0.f;
  for (int kc = 0; kc < NK; kc++)
    s += P[((size_t)kc * Z + z) * (4096 * 64) + r];
  C[(size_t)m * ldc + (size_t)z * Cz + n] = s;
}

// ---------------- GEMM: C = A @ Bt^T, 128x128 tile, mfma 16x16x32 bf16 -------
// A is bf16; M must be a multiple of 128, K a multiple of 32, B padded to the
// staged 128-row tiles (predication only in the epilogue).
// Staging: global_load_lds dwordx4, linear [128][32] LDS, double-buffered,
// ONE __syncthreads per K-step (prefetch of step k+1 flies under MFMA of k).
// EPI: 2 bf16+bias(dual-dtype), 3 bf16, 4 final select.
template<int EPI>
__global__ __launch_bounds__(256)
void rim_gemm(const u16* __restrict__ A16, long A0, long lda, long Az,
              const u16* __restrict__ B_, long Bz,
              void* __restrict__ C_, long C0, long ldc, long Cz,
              int M, int N, int K,
              const void* __restrict__ bias,
              const u16* __restrict__ hyp,
              const float* __restrict__ maskp,
              const void* __restrict__ hsp,
              const int* __restrict__ flagp)
{
  __shared__ __align__(16) __bf16 As[2][128 * 32];
  __shared__ __align__(16) __bf16 Bs[2][128 * 32];
  const int f = flagp[0];
  const int t = threadIdx.x;

  // XCD-aware bijective remap: each XCD gets a contiguous chunk of the
  // m-major block ordering (neighboring m-blocks share the B panel in L2).
  int gx = gridDim.x, gy = gridDim.y;
  int nwg = gx * gy * (int)gridDim.z;
  int wg = blockIdx.x + gx * (blockIdx.y + gy * blockIdx.z);
  {
    int q = nwg >> 3, r = nwg & 7, xc = wg & 7, ix = wg >> 3;
    wg = (xc < r ? xc * (q + 1) : r * (q + 1) + (xc - r) * q) + ix;
  }
  const int mb = wg % gx;
  const int nb = (wg / gx) % gy;
  const int z  = wg / (gx * gy);
  const int m0 = mb * 128, n0 = nb * 128;

  const __bf16* Ab = reinterpret_cast<const __bf16*>(A16) + (size_t)A0 +
                     (size_t)z * Az + (size_t)m0 * lda;
  const __bf16* Bb = reinterpret_cast<const __bf16*>(B_) + (size_t)z * Bz +
                     (size_t)n0 * (size_t)K;

  const int lane = t & 63, w = t >> 6;
  const int srow = lane >> 2;
  const int skq  = (lane & 3) * 8;
  const __bf16* aS0 = Ab + (size_t)(w * 16 + srow) * lda + skq;
  const __bf16* aS1 = Ab + (size_t)((w + 4) * 16 + srow) * lda + skq;
  const __bf16* bS0 = Bb + (size_t)(w * 16 + srow) * (size_t)K + skq;
  const __bf16* bS1 = Bb + (size_t)((w + 4) * 16 + srow) * (size_t)K + skq;

  const int wm = (w & 1) * 64, wn = (w >> 1) * 64;
  const int lr = lane & 15, lk = (lane >> 4) * 8;

  f32x4 acc[4][4];
#pragma unroll
  for (int i = 0; i < 4; i++)
#pragma unroll
    for (int j = 0; j < 4; j++)
#pragma unroll
      for (int r = 0; r < 4; r++) acc[i][j][r] = 0.f;

  auto STAGE = [&](int buf, int k0) {
    gload16(aS0 + k0, &As[buf][w * 512]);
    gload16(aS1 + k0, &As[buf][(w + 4) * 512]);
    gload16(bS0 + k0, &Bs[buf][w * 512]);
    gload16(bS1 + k0, &Bs[buf][(w + 4) * 512]);
  };

  STAGE(0, 0);
  int cur = 0;
  for (int k0 = 0; k0 < K; k0 += 32) {
    __syncthreads();   // drains vmcnt (stage of buf[cur]) + lgkmcnt (prev reads)
    if (k0 + 32 < K) STAGE(cur ^ 1, k0 + 32);   // prefetch flies under MFMA
    bf16x8 af[4], bg[4];
#pragma unroll
    for (int i = 0; i < 4; i++)
      af[i] = *reinterpret_cast<const bf16x8*>(&As[cur][(wm + i * 16 + lr) * 32 + lk]);
#pragma unroll
    for (int j = 0; j < 4; j++)
      bg[j] = *reinterpret_cast<const bf16x8*>(&Bs[cur][(wn + j * 16 + lr) * 32 + lk]);
#pragma unroll
    for (int i = 0; i < 4; i++)
#pragma unroll
      for (int j = 0; j < 4; j++)
        acc[i][j] = __builtin_amdgcn_mfma_f32_16x16x32_bf16(af[i], bg[j], acc[i][j], 0, 0, 0);
    cur ^= 1;
  }

  const int rq = (lane >> 4) * 4;  // C/D: row=(lane>>4)*4+reg, col=lane&15
  const int cq = lane & 15;
#pragma unroll
  for (int i = 0; i < 4; i++) {
#pragma unroll
    for (int j = 0; j < 4; j++) {
      int cg = n0 + wn + j * 16 + cq;
      if (cg >= N) continue;
#pragma unroll
      for (int r = 0; r < 4; r++) {
        int rg = m0 + wm + i * 16 + rq + r;
        if (rg >= M) continue;
        float v = acc[i][j][r];
        size_t cidx = (size_t)rg * ldc + (size_t)z * Cz + cg;
        if constexpr (EPI == 2) {
          f2bf((u16*)C_, C0 + cidx, v + ldin(bias, cg, f));
        } else if constexpr (EPI == 3) {
          f2bf((u16*)C_, C0 + cidx, v);
        } else {
          float mk = maskp[(size_t)rg * 6 + z];
          if (mk > 0.5f) {
            float o = v + bf2f(hyp, cidx);
            if (f) f2bf((u16*)C_, C0 + cidx, o);
            else   reinterpret_cast<float*>(C_)[C0 + cidx] = o;
          } else {
            if (f) reinterpret_cast<u16*>(C_)[C0 + cidx] =
                       reinterpret_cast<const u16*>(hsp)[C0 + cidx];
            else   reinterpret_cast<float*>(C_)[C0 + cidx] =
                       reinterpret_cast<const float*>(hsp)[C0 + cidx];
          }
        }
      }
    }
  }
}

// --------- fused pair GEMM: z<6 -> descriptor set 1 (Ggh), else set 2 -------
// Same proven 128x128 body; EPI=3 only. Doubles resident blocks for the two
// independent GRU projections (576+576 ragged -> 1152 fused, one tail).
__global__ __launch_bounds__(256)
void rim_gemm_pair(const u16* __restrict__ A1, long A01, long lda1, long Az1,
                   const u16* __restrict__ B1, long Bz1,
                   u16* __restrict__ C1, int K1,
                   const u16* __restrict__ A2, long A02, long lda2, long Az2,
                   const u16* __restrict__ B2, long Bz2,
                   u16* __restrict__ C2, int K2,
                   long ldc, long Cz, int M, int N)
{
  __shared__ __align__(16) __bf16 As[2][128 * 32];
  __shared__ __align__(16) __bf16 Bs[2][128 * 32];
  const int t = threadIdx.x;

  int gx = gridDim.x, gy = gridDim.y;
  int nwg = gx * gy * (int)gridDim.z;
  int wg = blockIdx.x + gx * (blockIdx.y + gy * blockIdx.z);
  {
    int q = nwg >> 3, r = nwg & 7, xc = wg & 7, ix = wg >> 3;
    wg = (xc < r ? xc * (q + 1) : r * (q + 1) + (xc - r) * q) + ix;
  }
  const int mb = wg % gx;
  const int nb = (wg / gx) % gy;
  const int zz = wg / (gx * gy);
  const int m0 = mb * 128, n0 = nb * 128;

  const int sel = (zz < 6) ? 0 : 1;
  const int z   = sel ? zz - 6 : zz;
  const int K   = sel ? K2 : K1;
  const __bf16* Ab = sel
      ? reinterpret_cast<const __bf16*>(A2) + (size_t)A02 + (size_t)z * Az2 +
        (size_t)m0 * lda2
      : reinterpret_cast<const __bf16*>(A1) + (size_t)A01 + (size_t)z * Az1 +
        (size_t)m0 * lda1;
  const long lda = sel ? lda2 : lda1;
  const __bf16* Bb = sel
      ? reinterpret_cast<const __bf16*>(B2) + (size_t)z * Bz2 + (size_t)n0 * K
      : reinterpret_cast<const __bf16*>(B1) + (size_t)z * Bz1 + (size_t)n0 * K;
  u16* Cp = sel ? C2 : C1;

  const int lane = t & 63, w = t >> 6;
  const int srow = lane >> 2;
  const int skq  = (lane & 3) * 8;
  const __bf16* aS0 = Ab + (size_t)(w * 16 + srow) * lda + skq;
  const __bf16* aS1 = Ab + (size_t)((w + 4) * 16 + srow) * lda + skq;
  const __bf16* bS0 = Bb + (size_t)(w * 16 + srow) * (size_t)K + skq;
  const __bf16* bS1 = Bb + (size_t)((w + 4) * 16 + srow) * (size_t)K + skq;

  const int wm = (w & 1) * 64, wn = (w >> 1) * 64;
  const int lr = lane & 15, lk = (lane >> 4) * 8;

  f32x4 acc[4][4];
#pragma unroll
  for (int i = 0; i < 4; i++)
#pragma unroll
    for (int j = 0; j < 4; j++)
#pragma unroll
      for (int r = 0; r < 4; r++) acc[i][j][r] = 0.f;

  auto STAGE = [&](int buf, int k0) {
    gload16(aS0 + k0, &As[buf][w * 512]);
    gload16(aS1 + k0, &As[buf][(w + 4) * 512]);
    gload16(bS0 + k0, &Bs[buf][w * 512]);
    gload16(bS1 + k0, &Bs[buf][(w + 4) * 512]);
  };

  STAGE(0, 0);
  int cur = 0;
  for (int k0 = 0; k0 < K; k0 += 32) {
    __syncthreads();
    if (k0 + 32 < K) STAGE(cur ^ 1, k0 + 32);
    bf16x8 af[4], bg[4];
#pragma unroll
    for (int i = 0; i < 4; i++)
      af[i] = *reinterpret_cast<const bf16x8*>(&As[cur][(wm + i * 16 + lr) * 32 + lk]);
#pragma unroll
    for (int j = 0; j < 4; j++)
      bg[j] = *reinterpret_cast<const bf16x8*>(&Bs[cur][(wn + j * 16 + lr) * 32 + lk]);
#pragma unroll
    for (int i = 0; i < 4; i++)
#pragma unroll
      for (int j = 0; j < 4; j++)
        acc[i][j] = __builtin_amdgcn_mfma_f32_16x16x32_bf16(af[i], bg[j], acc[i][j], 0, 0, 0);
    cur ^= 1;
  }

  const int rq = (lane >> 4) * 4;
  const int cq = lane & 15;
#pragma unroll
  for (int i = 0; i < 4; i++) {
#pragma unroll
    for (int j = 0; j < 4; j++) {
      int cg = n0 + wn + j * 16 + cq;
      if (cg >= N) continue;
#pragma unroll
      for (int r = 0; r < 4; r++) {
        int rg = m0 + wm + i * 16 + rq + r;
        if (rg >= M) continue;
        f2bf(Cp, (size_t)rg * ldc + (size_t)z * Cz + cg, acc[i][j][r]);
      }
    }
  }
}

// ------- tiled transpose to bf16: out[z][n][k] = cvt(in[z][k][n]) -----------
// Rows n in [N, Np) are zero-filled (B-tile padding for the MFMA GEMM).
__global__ __launch_bounds__(256)
void rim_transpose(const void* __restrict__ in, u16* __restrict__ out,
                   int N, int Np, int K, long in_z, long out_z,
                   const int* __restrict__ flagp)
{
  const int f = flagp[0];
  __shared__ float tile[32][33];
  int z = blockIdx.z;
  int k0 = blockIdx.x * 32, n0 = blockIdx.y * 32;
  int c = threadIdx.x & 31, r = threadIdx.x >> 5;
  for (int rr = r; rr < 32; rr += 8) {
    int k = k0 + rr, n = n0 + c;
    tile[rr][c] = (k < K && n < N)
        ? ldin(in, (size_t)z * in_z + (size_t)k * N + n, f) : 0.f;
  }
  __syncthreads();
  for (int rr = r; rr < 32; rr += 8) {
    int n = n0 + rr, k = k0 + c;
    if (n < Np && k < K)
      f2bf(out, (size_t)z * out_z + (size_t)n * K + k, tile[c][rr]);
  }
}

// ------- combined GRU weight, tiled transpose: out[u][o][i]=sum_s sw*gw[s][i][o]
// Output i-dim padded to IVp (zero-filled for i >= IVs).
__global__ __launch_bounds__(256)
void rim_gruw(const void* __restrict__ sw, const void* __restrict__ gw,
              u16* __restrict__ out, int IVp, int IVs,
              const int* __restrict__ flagp)
{
  const int f = flagp[0];
  __shared__ float lds[64 * 17];
  int u = blockIdx.z;
  int i0 = blockIdx.x * 16, o0 = blockIdx.y * 64;
  int t = threadIdx.x;
  float s0 = ldin(sw, u * 4 + 0, f), s1 = ldin(sw, u * 4 + 1, f);
  float s2 = ldin(sw, u * 4 + 2, f), s3 = ldin(sw, u * 4 + 3, f);
  int oo = t & 63, iq = t >> 6;
  size_t pl = (size_t)IVs * 1536;
#pragma unroll
  for (int r = 0; r < 4; r++) {
    int ii = iq * 4 + r;
    float acc = 0.f;
    if (i0 + ii < IVs) {
      size_t base = (size_t)(i0 + ii) * 1536 + o0 + oo;
      acc = s0 * ldin(gw, base, f) + s1 * ldin(gw, pl + base, f) +
            s2 * ldin(gw, 2 * pl + base, f) + s3 * ldin(gw, 3 * pl + base, f);
    }
    lds[oo * 17 + ii] = acc;
  }
  __syncthreads();
  int ow = t >> 2, iw = (t & 3) * 4;
  u16x4 pk;
#pragma unroll
  for (int j = 0; j < 4; j++) pk[j] = bfbits(lds[ow * 17 + iw + j]);
  *reinterpret_cast<u16x4*>(out + ((size_t)u * 1536 + o0 + ow) * IVp + i0 + iw) = pk;
}

// ---------------- scores / top-4 mask / 2-way softmax / inputs ----------------
// inputs written K-padded to 416 (zeros in [400,416)).
__global__ __launch_bounds__(256)
void rim_scores(const float* __restrict__ q_l, const float* __restrict__ k_l0,
                const void* __restrict__ bk, const u16* __restrict__ v_l0,
                const void* __restrict__ bv, float* __restrict__ maskf,
                u16* __restrict__ inputs, const int* __restrict__ flagp)
{
  const int f = flagp[0];
  int b = blockIdx.x;
  int t = threadIdx.x;
  int lane = t & 63;
  __shared__ float s0[6], s1[6], sm[6], sp[6];
  if (t < 64) {
    float kv = k_l0[(size_t)b * 64 + lane];
    for (int u = 0; u < 6; u++) {
      float p = q_l[((size_t)b * 6 + u) * 64 + lane] * kv;
      for (int off = 32; off; off >>= 1) p += __shfl_down(p, off);
      if (lane == 0) s0[u] = p * 0.125f;
    }
  } else if (t < 128) {
    float kv = ldin(bk, lane, f);
    for (int u = 0; u < 6; u++) {
      float p = q_l[((size_t)b * 6 + u) * 64 + lane] * kv;
      for (int off = 32; off; off >>= 1) p += __shfl_down(p, off);
      if (lane == 0) s1[u] = p * 0.125f;
    }
  }
  __syncthreads();
  if (t == 0) {
    for (int u = 0; u < 6; u++) {
      int cnt = 0;
      for (int u2 = 0; u2 < 6; u2++)
        if (s0[u2] > s0[u] || (s0[u2] == s0[u] && u2 < u)) cnt++;
      float mk = (cnt < 4) ? 1.0f : 0.0f;
      sm[u] = mk;
      maskf[(size_t)b * 6 + u] = mk;
      sp[u] = 1.0f / (1.0f + expf(s1[u] - s0[u]));
    }
  }
  __syncthreads();
  for (int idx = t; idx < 2496; idx += 256) {
    int u = idx / 416, j = idx - u * 416;
    float val = 0.f;
    if (j < 400)
      val = sm[u] * (sp[u] * bf2f(v_l0, (size_t)b * 400 + j) +
                     (1.0f - sp[u]) * ldin(bv, j, f));
    f2bf(inputs, ((size_t)b * 6 + u) * 416 + j, val);
  }
}

// ---------------- GRU elementwise (8-wide vectorized) ----------------
// one thread handles 8 consecutive h; total must be a multiple of 2048.
__global__ __launch_bounds__(256)
void rim_gru(const u16* __restrict__ Ggx, const u16* __restrict__ Ggh,
             const void* __restrict__ hs, long R0,
             u16* __restrict__ hy, long total8,
             const int* __restrict__ flagp)
{
  const int f = flagp[0];
  long i8 = (long)blockIdx.x * 256 + threadIdx.x;
  if (i8 >= total8) return;
  long bu = i8 >> 6;            // (i8*8) >> 9
  int h0 = (int)(i8 & 63) * 8;
  size_t gb = ((size_t)bu * 1536 + h0) >> 3;   // bf16x8 index
  const bf16x8* gx8 = reinterpret_cast<const bf16x8*>(Ggx);
  const bf16x8* gh8 = reinterpret_cast<const bf16x8*>(Ggh);
  bf16x8 xr8 = gx8[gb], xz8 = gx8[gb + 64], xn8 = gx8[gb + 128];
  bf16x8 hr8 = gh8[gb], hz8 = gh8[gb + 64], hn8 = gh8[gb + 128];
  float hv[8];
  size_t base = (size_t)R0 + (size_t)i8 * 8;
  if (f) {
    bf16x8 h8 = *reinterpret_cast<const bf16x8*>(
        reinterpret_cast<const __bf16*>(hs) + base);
#pragma unroll
    for (int j = 0; j < 8; j++) hv[j] = (float)h8[j];
  } else {
    f32x4 lo = *reinterpret_cast<const f32x4*>(
        reinterpret_cast<const float*>(hs) + base);
    f32x4 hi = *reinterpret_cast<const f32x4*>(
        reinterpret_cast<const float*>(hs) + base + 4);
#pragma unroll
    for (int j = 0; j < 4; j++) { hv[j] = lo[j]; hv[j + 4] = hi[j]; }
  }
  bf16x8 out;
#pragma unroll
  for (int j = 0; j < 8; j++) {
    float xr = (float)xr8[j], xz = (float)xz8[j], xn = (float)xn8[j];
    float hr = (float)hr8[j], hz = (float)hz8[j], hn = (float)hn8[j];
    float r = 1.f / (1.f + expf(-(xr + hr)));
    float zz = 1.f / (1.f + expf(-(xz + hz)));
    float n = tanhf(xn + r * hn);
    out[j] = (__bf16)(n + zz * (hv[j] - n));
  }
  *reinterpret_cast<bf16x8*>(hy + i8 * 8) = out;
}

// ---------------- per-b attention: att -> softmax*mask -> ctx ----------------
// comb layout per b: [u][2304] = [q 128 | k 128 | v 2048]. PV 8-wide.
__global__ __launch_bounds__(256)
void rim_attn(const u16* __restrict__ comb, const float* __restrict__ maskp,
              u16* __restrict__ ctx)
{
  int bl = blockIdx.x;
  int t = threadIdx.x;
  const __bf16* cb = reinterpret_cast<const __bf16*>(comb) + (size_t)bl * 13824;
  __shared__ float qs[1536];
  __shared__ float aps[144];
  __shared__ __align__(16) u16 vs[12288];
  // q|k load: 192 groups of 8 bf16 -> f32 LDS
  if (t < 192) {
    int u = t >> 5, r8 = t & 31;
    bf16x8 q8 = *reinterpret_cast<const bf16x8*>(cb + u * 2304 + r8 * 8);
#pragma unroll
    for (int j = 0; j < 8; j++) qs[u * 256 + r8 * 8 + j] = (float)q8[j];
  }
  // v load: vs[u*2048 + e] = v[u][e]
  for (int idx = t; idx < 1536; idx += 256) {
    int u = idx >> 8, r = idx & 255;
    *reinterpret_cast<bf16x8*>(&vs[idx * 8]) =
        *reinterpret_cast<const bf16x8*>(cb + u * 2304 + 256 + r * 8);
  }
  __syncthreads();
  if (t < 144) {
    int h = t / 36, r6 = t % 36, uq = r6 / 6, uk = r6 % 6;
    float s = 0.f;
#pragma unroll
    for (int d = 0; d < 32; d++)
      s += qs[uq * 256 + h * 32 + d] * qs[uk * 256 + 128 + h * 32 + d];
    aps[t] = s * 0.17677669529663687f;
  }
  __syncthreads();
  if (t < 24) {
    int h = t / 6, uq = t % 6;
    float* row = &aps[h * 36 + uq * 6];
    float mx = row[0];
    for (int k = 1; k < 6; k++) mx = fmaxf(mx, row[k]);
    float e[6], sum = 0.f;
    for (int k = 0; k < 6; k++) { e[k] = expf(row[k] - mx); sum += e[k]; }
    float mk = maskp[(size_t)bl * 6 + uq] / sum;
    for (int k = 0; k < 6; k++) row[k] = e[k] * mk;
  }
  __syncthreads();
  // PV: 1536 groups of 8 consecutive outputs; 6 x 16B LDS reads per group
  for (int g8 = t; g8 < 1536; g8 += 256) {
    int uq = g8 >> 8;
    int g0 = (g8 & 255) * 8;
    int h  = g0 >> 9;
    const float* ar = &aps[h * 36 + uq * 6];
    float acc[8];
#pragma unroll
    for (int j = 0; j < 8; j++) acc[j] = 0.f;
#pragma unroll
    for (int k = 0; k < 6; k++) {
      bf16x8 vv = *reinterpret_cast<const bf16x8*>(&vs[k * 2048 + g0]);
      float a = ar[k];
#pragma unroll
      for (int j = 0; j < 8; j++) acc[j] += a * (float)vv[j];
    }
    bf16x8 ov;
#pragma unroll
    for (int j = 0; j < 8; j++) ov[j] = (__bf16)acc[j];
    *reinterpret_cast<bf16x8*>(
        &ctx[(((size_t)bl * 6 + uq) * 2048 + g0)]) = ov;
  }
}

// ---------------- host ----------------
extern "C" void kernel_launch(void* const* d_in, const int* in_sizes, int n_in,
                              void* d_out, int out_size, void* d_ws, size_t ws_size,
                              hipStream_t stream)
{
  (void)in_sizes; (void)n_in; (void)out_size;
  const void* x   = d_in[0];
  const void* hs  = d_in[1];
  const void* Wk  = d_in[2];
  const void* bk  = d_in[3];
  const void* Wv  = d_in[4];
  const void* bv  = d_in[5];
  const void* Wq  = d_in[6];
  const void* Wq_ = d_in[7];
  const void* Wk_ = d_in[8];
  const void* Wv_ = d_in[9];
  const void* Wo_ = d_in[10];
  const void* sw  = d_in[11];
  const void* gwx = d_in[12];
  const void* gwh = d_in[13];
  char* ws = (char*)d_ws;

  int*   flagp = (int*)(ws + OFF_FLAG);
  float* maskf = (float*)(ws + OFF_MASK);
  u16* WvT   = (u16*)(ws + OFF_WVT);
  u16* WQKV  = (u16*)(ws + OFF_WQKV);
  u16* WoT   = (u16*)(ws + OFF_WOT);
  u16* WxcT  = (u16*)(ws + OFF_WXCT);
  u16* WhcT  = (u16*)(ws + OFF_WHCT);
  u16* hy    = (u16*)(ws + OFF_HY);
  u16* xb    = (u16*)(ws + OFF_XB);
  u16* hsb   = (u16*)(ws + OFF_HSB);
  u16* inputs = (u16*)(ws + A_INP);
  float* PK   = (float*)(ws + A_PK);
  float* PQ   = (float*)(ws + A_PQ);
  float* k_l0 = (float*)(ws + A_KL);
  float* q_l  = (float*)(ws + A_QL);
  u16* v_l0   = (u16*)(ws + A_VL);

  int R2 = 256, R3 = 256;
  {
    const int cand[5] = {4096, 2048, 1024, 512, 256};
    for (int i = 0; i < 5; i++)
      if (A_P1 + (size_t)cand[i] * 36864 <= ws_size) { R2 = cand[i]; break; }
    for (int i = 0; i < 5; i++)
      if (ARENA + (size_t)cand[i] * 52224 <= ws_size) { R3 = cand[i]; break; }
  }

  rim_detect<<<dim3(1), dim3(64), 0, stream>>>(sw, flagp);

  rim_cast<<<dim3(2048), dim3(256), 0, stream>>>(x, xb, 524288L, flagp);
  rim_cast<<<dim3(2048), dim3(256), 0, stream>>>(hs, hsb, 1572864L, flagp);

  auto T = [&](const void* in, u16* outp, int N, int Np, int K, long iz, long oz,
               int Z) {
    dim3 g((K + 31) / 32, (Np + 31) / 32, Z);
    rim_transpose<<<g, dim3(256), 0, stream>>>(in, outp, N, Np, K, iz, oz, flagp);
  };
  T(Wv, WvT, 400, 512, 1024, 0, 0, 1);
  T(Wq_, WQKV, 128, 128, 512, 65536, 1179648, 6);
  T(Wk_, WQKV + 65536, 128, 128, 512, 65536, 1179648, 6);
  T(Wv_, WQKV + 131072, 2048, 2048, 512, 1048576, 1179648, 6);
  T(Wo_, WoT, 512, 512, 2048, 1048576, 1048576, 6);
  rim_gruw<<<dim3(26, 24, 6), dim3(256), 0, stream>>>(sw, gwx, WxcT, 416, 400, flagp);
  rim_gruw<<<dim3(32, 24, 6), dim3(256), 0, stream>>>(sw, gwh, WhcT, 512, 512, flagp);

  auto G = [&](int epi, const void* A, long A0, long lda, long Az,
               const u16* B, long Bz, void* C, long C0, long ldc, long Cz,
               int M, int N, int K, int Z,
               const void* bias, const u16* hyp, const float* mp, const void* hsp) {
    dim3 g((M + 127) / 128, (N + 127) / 128, Z), blk(256);
    if (epi == 2)
      rim_gemm<2><<<g, blk, 0, stream>>>((const u16*)A, A0, lda, Az, B, Bz, C, C0,
                                         ldc, Cz, M, N, K, bias, hyp, mp, hsp, flagp);
    else if (epi == 3)
      rim_gemm<3><<<g, blk, 0, stream>>>((const u16*)A, A0, lda, Az, B, Bz, C, C0,
                                         ldc, Cz, M, N, K, bias, hyp, mp, hsp, flagp);
    else
      rim_gemm<4><<<g, blk, 0, stream>>>((const u16*)A, A0, lda, Az, B, Bz, C, C0,
                                         ldc, Cz, M, N, K, bias, hyp, mp, hsp, flagp);
  };

  // scores path: f32 split-K SGEMM (exact products -> stable top-k)
  rim_sgemm32<<<dim3(128, 4, 1), dim3(256), 0, stream>>>(
      x, 1024, 0, Wk, 0, PK, 256, flagp);
  rim_sgemm32<<<dim3(128, 2, 6), dim3(256), 0, stream>>>(
      hs, 3072, 512, Wq, 32768, PQ, 256, flagp);
  rim_sreduce<<<dim3(1024), dim3(256), 0, stream>>>(
      PK, 4, 1, k_l0, 64, 0, bk, flagp, 4096L * 64);
  rim_sreduce<<<dim3(6144), dim3(256), 0, stream>>>(
      PQ, 2, 6, q_l, 384, 64, nullptr, flagp, 6L * 4096 * 64);
  G(2, xb, 0, 1024, 0, WvT, 0, v_l0, 0, 400, 0, 4096, 400, 1024, 1,
    bv, nullptr, nullptr, nullptr);
  rim_scores<<<dim3(4096), dim3(256), 0, stream>>>(q_l, k_l0, bk, v_l0, bv,
                                                   maskf, inputs, flagp);

  // GRU projections: one fused z=12 dispatch per chunk (Ggh | Ggx)
  u16* Ggx = (u16*)(ws + A_P1);
  u16* Ggh = (u16*)(ws + A_P1 + (size_t)R2 * 18432);
  for (int r0 = 0; r0 < 4096; r0 += R2) {
    dim3 g(R2 / 128, 12, 12), blk(256);
    rim_gemm_pair<<<g, blk, 0, stream>>>(
        hsb, (long)r0 * 3072, 3072, 512, WhcT, 786432, Ggh, 512,
        inputs, (long)r0 * 2496, 2496, 416, WxcT, 638976, Ggx, 416,
        9216, 1536, R2, 1536);
    long total8 = (long)R2 * 3072 / 8;
    rim_gru<<<dim3((unsigned)(total8 / 256)), dim3(256), 0, stream>>>(
        Ggx, Ggh, hs, (long)r0 * 3072, hy + (size_t)r0 * 3072, total8, flagp);
  }

  // attention + output in chunks of R3 rows (q|k|v projections fused, N=2304)
  u16* comb  = (u16*)(ws + ARENA);
  u16* ctx_c = (u16*)(ws + ARENA + (size_t)R3 * 27648);
  for (int r0 = 0; r0 < 4096; r0 += R3) {
    G(3, hy, (long)r0 * 3072, 3072, 512, WQKV, 1179648, comb, 0, 13824, 2304,
      R3, 2304, 512, 6, nullptr, nullptr, nullptr, nullptr);
    rim_attn<<<dim3(R3), dim3(256), 0, stream>>>(comb, maskf + (size_t)r0 * 6, ctx_c);
    G(4, ctx_c, 0, 12288, 2048, WoT, 1048576, d_out, (long)r0 * 3072, 3072, 512,
      R3, 512, 2048, 6, nullptr, hy + (size_t)r0 * 3072, maskf + (size_t)r0 * 6, hs);
  }
}